// Round 7
// baseline (207.604 us; speedup 1.0000x reference)
//
#include <hip/hip_runtime.h>
#include <stdint.h>

#define ROWS   4096
#define NCOL   8192
#define TARGET 7680
#define NW     (NCOL - TARGET + 1)   // 513 windows
#define NT     512                   // threads per block (8 waves)
#define VPT    (NCOL / NT)           // 16 values per thread per row
#define NB     2048                  // histogram bins
#define BPT    (NB / NT)             // 4 bins per thread in scan
#define NWAVE  (NT / 64)             // 8 waves
#define SCAP   2048                  // sorted-buffer capacity (typ. tot ~1035)
#define MAXS   (SCAP / NT)           // max slots per thread in fixup (4)
#define RPB    2                     // rows per block, phase-INTERLEAVED
#define GRID   (ROWS / RPB)          // 2048 blocks

// One row's LDS working set (24688 B). Two per block = 48.2 KB -> 3 blocks/CU.
struct Half {
    uint32_t hist[NB];      // identity layout (bin b at hist[b])
    float    sorted[SCAP];  // scattered candidates (unordered within bin)
    float    sorted2[SCAP]; // fixup output: exact sorted tails
    uint32_t wsum[NWAVE];
    uint32_t res[4];        // [0]=B_lo [1]=cntB(incl) [2]=B_hi [3]=topBase(excl)
    float    fmin[NWAVE], fmax[NWAVE];
};

// Per-row register state. Statically indexed arrays -> stays in VGPRs.
struct RState {
    float    v[VPT];
    uint32_t binPk[VPT / 2];
    float    mn, mx, scale1;
    int      degen;                 // block-uniform per row
    uint32_t h[BPT];                // scan temporaries (live across S3)
    uint32_t s0, sc;
    int      B_lo, B_hi;
    uint32_t cntB, topBase, shiftT, tot;
};

// v in [mn,mx] guaranteed -> (v-mn)*s >= 0 exactly; only upper clamp needed.
__device__ __forceinline__ int bin1f(float v, float mn, float s) {
    int b = (int)((v - mn) * s);
    return b > NB - 1 ? NB - 1 : b;
}

// ---- phase bodies (all forceinline; A/B calls interleave for ILP) ----

__device__ __forceinline__ void ph_load(const float* __restrict__ x, int row,
                                        int tid, RState& r) {
    const float4* xv = (const float4*)(x + (size_t)row * NCOL);
    #pragma unroll
    for (int j = 0; j < VPT / 4; j++) {
        float4 t = xv[tid + j * NT];
        r.v[4 * j + 0] = t.x; r.v[4 * j + 1] = t.y;
        r.v[4 * j + 2] = t.z; r.v[4 * j + 3] = t.w;
    }
    float mn = r.v[0], mx = r.v[0];
    #pragma unroll
    for (int j = 1; j < VPT; j++) { mn = fminf(mn, r.v[j]); mx = fmaxf(mx, r.v[j]); }
    r.mn = mn; r.mx = mx;
}

__device__ __forceinline__ void ph_wave_minmax(Half& sm, RState& r, int lane, int wid) {
    float mn = r.mn, mx = r.mx;
    #pragma unroll
    for (int off = 32; off > 0; off >>= 1) {
        mn = fminf(mn, __shfl_down(mn, off, 64));
        mx = fmaxf(mx, __shfl_down(mx, off, 64));
    }
    if (lane == 0) { sm.fmin[wid] = mn; sm.fmax[wid] = mx; }
}

__device__ __forceinline__ void ph_final_minmax(Half& sm, RState& r) {
    float mn = sm.fmin[0], mx = sm.fmax[0];
    #pragma unroll
    for (int w = 1; w < NWAVE; w++) { mn = fminf(mn, sm.fmin[w]); mx = fmaxf(mx, sm.fmax[w]); }
    r.mn = mn; r.mx = mx;
    r.degen = !(mx > mn);                    // uniform across block
    r.scale1 = r.degen ? 0.0f : (float)NB / (mx - mn);
}

__device__ __forceinline__ void ph_hist(Half& sm, RState& r) {
    if (r.degen) return;                     // uniform branch
    #pragma unroll
    for (int j = 0; j < VPT; j += 2) {
        int b0 = bin1f(r.v[j],     r.mn, r.scale1);
        int b1 = bin1f(r.v[j + 1], r.mn, r.scale1);
        r.binPk[j >> 1] = (uint32_t)b0 | ((uint32_t)b1 << 16);
        atomicAdd(&sm.hist[b0], 1u);
        atomicAdd(&sm.hist[b1], 1u);
    }
}

__device__ __forceinline__ void ph_scan_pre(Half& sm, RState& r, int tid, int lane, int wid) {
    if (r.degen) return;
    uint4 hv = *(const uint4*)&sm.hist[tid * BPT];   // one ds_read_b128
    r.h[0] = hv.x; r.h[1] = hv.y; r.h[2] = hv.z; r.h[3] = hv.w;
    uint32_t s0 = hv.x + hv.y + hv.z + hv.w;
    uint32_t sc = s0;
    #pragma unroll
    for (int off = 1; off < 64; off <<= 1) {
        uint32_t n = __shfl_up(sc, off, 64);
        if (lane >= off) sc += n;
    }
    if (lane == 63) sm.wsum[wid] = sc;
    r.s0 = s0; r.sc = sc;
}

__device__ __forceinline__ void ph_scan_post(Half& sm, RState& r, int tid, int wid) {
    if (r.degen) return;
    uint32_t woff = 0;
    #pragma unroll
    for (int w = 0; w < NWAVE; w++) if (w < wid) woff += sm.wsum[w];
    const uint32_t incl = r.sc + woff, excl = incl - r.s0;
    const uint32_t ka = NW - 1, kb = TARGET - 1;
    if (ka >= excl && ka < incl) {           // bin of rank 512 (bottom tail end)
        uint32_t c = excl; bool done = false;
        #pragma unroll
        for (int j = 0; j < BPT; j++) {
            if (!done) {
                if (ka < c + r.h[j]) {
                    sm.res[0] = (uint32_t)(tid * BPT + j);
                    sm.res[1] = c + r.h[j];  // cntB = inclusive prefix at B_lo
                    done = true;
                } else c += r.h[j];
            }
        }
    }
    if (kb >= excl && kb < incl) {           // bin of rank 7679 (top tail start)
        uint32_t c = excl; bool done = false;
        #pragma unroll
        for (int j = 0; j < BPT; j++) {
            if (!done) {
                if (kb < c + r.h[j]) {
                    sm.res[2] = (uint32_t)(tid * BPT + j);
                    sm.res[3] = c;           // topBase = exclusive prefix at B_hi
                    done = true;
                } else c += r.h[j];
            }
        }
    }
    uint4 w4;                                // exclusive-prefix bases, b128 store
    uint32_t run = excl;
    w4.x = run; run += r.h[0];
    w4.y = run; run += r.h[1];
    w4.z = run; run += r.h[2];
    w4.w = run;
    *(uint4*)&sm.hist[tid * BPT] = w4;
}

__device__ __forceinline__ void ph_getres(Half& sm, RState& r) {
    if (r.degen) return;
    r.B_lo = (int)sm.res[0]; r.cntB   = sm.res[1];
    r.B_hi = (int)sm.res[2]; r.topBase = sm.res[3];
    r.shiftT = r.cntB - r.topBase;           // mod-2^32
    uint32_t tot = r.cntB + (uint32_t)NCOL - r.topBase;
    r.tot = tot > SCAP ? SCAP : tot;
}

__device__ __forceinline__ void ph_scatter(Half& sm, RState& r) {
    if (r.degen) return;
    #pragma unroll
    for (int j = 0; j < VPT; j++) {
        int b = (int)((r.binPk[j >> 1] >> ((j & 1) * 16)) & 0xffffu);
        if (b <= r.B_lo || b >= r.B_hi) {
            uint32_t pos = atomicAdd(&sm.hist[b], 1u);
            if (b >= r.B_hi) pos += r.shiftT;
            if (pos < SCAP) sm.sorted[pos] = r.v[j];
        }
    }
}

__device__ __forceinline__ void ph_fixup(Half& sm, RState& r, int tid) {
    if (r.degen) return;
    #pragma unroll
    for (int it = 0; it < MAXS; it++) {
        int s = tid + it * NT;
        if (s < (int)r.tot) {
            float vv = sm.sorted[s];
            int b = bin1f(vv, r.mn, r.scale1);
            uint32_t en = sm.hist[b];
            uint32_t st;
            if (s < (int)r.cntB) {
                st = (b == 0) ? 0u : sm.hist[b - 1];
            } else {
                st = (b == r.B_hi) ? r.topBase : sm.hist[b - 1];
                st += r.shiftT; en += r.shiftT;
            }
            if (en > r.tot) en = r.tot;
            uint32_t rr = 0;
            if (en - st > 1) {
                for (uint32_t q = st; q < en; q++) {
                    float u = sm.sorted[q];
                    rr += (u < vv) || (u == vv && (int)q < s);
                }
            }
            uint32_t d = st + rr;
            if (d < SCAP) sm.sorted2[d] = vv;
        }
    }
}

__device__ __forceinline__ void ph_argmin(Half& sm, RState& r, int row, int lane,
                                          float* __restrict__ out) {
    if (r.degen) {
        if (lane == 0) { out[row] = r.mn; out[ROWS + row] = r.mn; }
        return;
    }
    const int topstart = (int)r.tot - NW;
    float lbest = __int_as_float(0x7F800000);   // +inf
    int   lidx  = 0x7FFFFFFF;
    for (int i = lane; i < NW; i += 64) {
        float len = sm.sorted2[topstart + i] - sm.sorted2[i];
        if (len < lbest) { lbest = len; lidx = i; }
    }
    #pragma unroll
    for (int off = 32; off > 0; off >>= 1) {
        float v2 = __shfl_down(lbest, off, 64);
        int   i2 = __shfl_down(lidx,  off, 64);
        if (v2 < lbest || (v2 == lbest && i2 < lidx)) { lbest = v2; lidx = i2; }
    }
    if (lane == 0) {
        out[row]        = sm.sorted2[lidx];             // left  = s[idx]
        out[ROWS + row] = sm.sorted2[topstart + lidx];  // right = s[idx+target-1]
    }
}

// (NT,2): no forced VGPR ceiling ((512,8) spilled in round 3). Expected ~110
// VGPR -> LDS-limited to 3 blocks/CU = 24 waves, 6 rows in flight per CU.
// 2 rows per block INTERLEAVED per phase: 3 barriers/row instead of 6, and two
// independent dependency chains per wave hide each other's LDS/shuffle latency.
// Grid 2048 with 3 resident/CU leaves a large refill pool (round-5's RPB=4
// convoy had zero pool -> lockstep; not the case here).
__global__ __launch_bounds__(NT, 2)
void recall_window_kernel(const float* __restrict__ x, float* __restrict__ out) {
    __shared__ Half smA, smB;
    const int tid = threadIdx.x;
    const int lane = tid & 63, wid = tid >> 6;
    const int rowA = blockIdx.x * RPB, rowB = rowA + 1;
    RState ra, rb;

    ph_load(x, rowA, tid, ra);               // 8 global loads issued up front
    ph_load(x, rowB, tid, rb);
    ph_wave_minmax(smA, ra, lane, wid);
    ph_wave_minmax(smB, rb, lane, wid);
    #pragma unroll
    for (int j = 0; j < BPT; j++) {
        smA.hist[tid + j * NT] = 0;
        smB.hist[tid + j * NT] = 0;
    }
    __syncthreads();                                             // S1
    ph_final_minmax(smA, ra);
    ph_final_minmax(smB, rb);

    ph_hist(smA, ra);
    ph_hist(smB, rb);
    __syncthreads();                                             // S2

    ph_scan_pre(smA, ra, tid, lane, wid);
    ph_scan_pre(smB, rb, tid, lane, wid);
    __syncthreads();                                             // S3

    ph_scan_post(smA, ra, tid, wid);
    ph_scan_post(smB, rb, tid, wid);
    __syncthreads();                                             // S4

    ph_getres(smA, ra);
    ph_getres(smB, rb);
    ph_scatter(smA, ra);
    ph_scatter(smB, rb);
    __syncthreads();                                             // S5

    ph_fixup(smA, ra, tid);
    ph_fixup(smB, rb, tid);
    __syncthreads();                                             // S6

    if (wid == 0)      ph_argmin(smA, ra, rowA, lane, out);   // waves run rows
    else if (wid == 1) ph_argmin(smB, rb, rowB, lane, out);   // concurrently
}

extern "C" void kernel_launch(void* const* d_in, const int* in_sizes, int n_in,
                              void* d_out, int out_size, void* d_ws, size_t ws_size,
                              hipStream_t stream) {
    const float* x = (const float*)d_in[0];
    float* out = (float*)d_out;
    recall_window_kernel<<<GRID, NT, 0, stream>>>(x, out);
}

// Round 8
// 191.347 us; speedup vs baseline: 1.0850x; 1.0850x over previous
//
#include <hip/hip_runtime.h>
#include <stdint.h>

#define ROWS   4096
#define NCOL   8192
#define TARGET 7680
#define NW     (NCOL - TARGET + 1)   // 513 windows
#define NT     256                   // threads per block (4 waves)
#define VPT    (NCOL / NT)           // 32 values per thread (in VGPRs)
#define NB     2048                  // histogram bins
#define BPT    (NB / NT)             // 8 bins per thread in scan
#define NWAVE  (NT / 64)             // 4 waves
#define SCAP   2048                  // sorted-buffer capacity (typ. tot ~1035)
#define MAXS   (SCAP / NT)           // max slots per thread in fixup (8)

struct Smem {
    uint32_t hist[NB];       // transposed: logical bin b at ((b&7)<<8)|(b>>3)
    float    sorted[SCAP];   // scattered candidates (unordered within bin)
    float    sorted2[SCAP];  // fixup output: exact sorted tails
    uint32_t wsum[NWAVE];
    uint32_t res[4];         // [0]=B_lo [1]=cntB(incl) [2]=B_hi [3]=topBase(excl)
    float    fmin[NWAVE], fmax[NWAVE];
};

// v in [mn,mx] guaranteed (block min/max) -> (v-mn)*s >= 0 exactly; only the
// upper clamp is needed (v==mx lands on NB).
__device__ __forceinline__ int bin1f(float v, float mn, float s) {
    int b = (int)((v - mn) * s);
    return b > NB - 1 ? NB - 1 : b;
}
// transposed physical index: scan reads hist[(j<<8)|tid] lane-consecutively
// (conflict-free); atomics hash on bin bits 3..7 (random for random values).
// (round-7 showed identity layout doubles bank conflicts: 2374 vs 969/block)
__device__ __forceinline__ int HIX(int b) { return ((b & 7) << 8) | (b >> 3); }

// NT=256: 4-wave barriers (vs 8) and LDS-limited 6 blocks/CU (vs wave-capped 4
// at NT=512) -> 6 rows in flight per CU. launch_bounds(256,4): 128-VGPR budget,
// no forced ceiling (round-3: forced 64 spilled). Expected ~80 VGPR, no spill.
// Round-7 lesson: 2-row interleave exceeds register budget -> compiler
// rematerializes loads (VGPR_Count=44, slow); one row per block, grid 4096.
__global__ __launch_bounds__(NT, 4)
void recall_window_kernel(const float* __restrict__ x, float* __restrict__ out) {
    __shared__ Smem sm;
    const int tid = threadIdx.x;
    const int row = blockIdx.x;
    const int lane = tid & 63, wid = tid >> 6;

    // ---- Load row into registers (coalesced 16B), min/max fused so the
    //      float4 staging temps die immediately (lower peak VGPR) ----
    float v[VPT];
    float mn = __int_as_float(0x7F800000), mx = -mn;
    const float4* xv = (const float4*)(x + (size_t)row * NCOL);
    #pragma unroll
    for (int j = 0; j < VPT / 4; j++) {
        float4 t = xv[tid + j * NT];
        v[4 * j + 0] = t.x; v[4 * j + 1] = t.y;
        v[4 * j + 2] = t.z; v[4 * j + 3] = t.w;
        mn = fminf(mn, fminf(fminf(t.x, t.y), fminf(t.z, t.w)));
        mx = fmaxf(mx, fmaxf(fmaxf(t.x, t.y), fmaxf(t.z, t.w)));
    }

    // ---- Block min/max (+ zero hist in same phase) ----
    #pragma unroll
    for (int off = 32; off > 0; off >>= 1) {
        mn = fminf(mn, __shfl_down(mn, off, 64));
        mx = fmaxf(mx, __shfl_down(mx, off, 64));
    }
    if (lane == 0) { sm.fmin[wid] = mn; sm.fmax[wid] = mx; }
    #pragma unroll
    for (int j = 0; j < BPT; j++) sm.hist[tid + j * NT] = 0;
    __syncthreads();                                             // S1
    #pragma unroll
    for (int w = 0; w < NWAVE; w++) {
        mn = fminf(mn, sm.fmin[w]);
        mx = fmaxf(mx, sm.fmax[w]);
    }

    if (!(mx > mn)) {   // all values equal (uniform branch)
        if (tid == 0) { out[row] = mn; out[ROWS + row] = mn; }
        return;
    }
    const float scale1 = (float)NB / (mx - mn);

    // ---- L1 histogram; cache each value's bin packed 2x16b (16 VGPR) so the
    //      scatter pass doesn't recompute fma/cvt/clamp per value ----
    uint32_t binPk[VPT / 2];
    #pragma unroll
    for (int j = 0; j < VPT; j += 2) {
        int b0 = bin1f(v[j],     mn, scale1);
        int b1 = bin1f(v[j + 1], mn, scale1);
        binPk[j >> 1] = (uint32_t)b0 | ((uint32_t)b1 << 16);
        atomicAdd(&sm.hist[HIX(b0)], 1u);
        atomicAdd(&sm.hist[HIX(b1)], 1u);
    }
    __syncthreads();                                             // S2

    // ---- Single scan: locate rank bins + write scatter bases ----
    uint32_t h[BPT], s0 = 0;
    #pragma unroll
    for (int j = 0; j < BPT; j++) { h[j] = sm.hist[(j << 8) | tid]; s0 += h[j]; }
    uint32_t sc = s0;
    #pragma unroll
    for (int off = 1; off < 64; off <<= 1) {
        uint32_t n = __shfl_up(sc, off, 64);
        if (lane >= off) sc += n;
    }
    if (lane == 63) sm.wsum[wid] = sc;
    __syncthreads();                                             // S3
    uint32_t woff = 0;
    #pragma unroll
    for (int w = 0; w < NWAVE; w++) if (w < wid) woff += sm.wsum[w];
    const uint32_t incl = sc + woff, excl = incl - s0;
    const uint32_t ka = NW - 1, kb = TARGET - 1;
    if (ka >= excl && ka < incl) {           // bin of rank 512 (bottom tail end)
        uint32_t c = excl; bool done = false;
        #pragma unroll
        for (int j = 0; j < BPT; j++) {
            if (!done) {
                if (ka < c + h[j]) {
                    sm.res[0] = (uint32_t)(tid * BPT + j);
                    sm.res[1] = c + h[j];    // cntB = inclusive prefix at B_lo
                    done = true;
                } else c += h[j];
            }
        }
    }
    if (kb >= excl && kb < incl) {           // bin of rank 7679 (top tail start)
        uint32_t c = excl; bool done = false;
        #pragma unroll
        for (int j = 0; j < BPT; j++) {
            if (!done) {
                if (kb < c + h[j]) {
                    sm.res[2] = (uint32_t)(tid * BPT + j);
                    sm.res[3] = c;           // topBase = exclusive prefix at B_hi
                    done = true;
                } else c += h[j];
            }
        }
    }
    {   // overwrite counts with exclusive-prefix bases (independent of res)
        uint32_t run = excl;
        #pragma unroll
        for (int j = 0; j < BPT; j++) { sm.hist[(j << 8) | tid] = run; run += h[j]; }
    }
    __syncthreads();                                             // S4
    const int      B_lo    = (int)sm.res[0];
    const uint32_t cntB    = sm.res[1];
    const int      B_hi    = (int)sm.res[2];
    const uint32_t topBase = sm.res[3];
    const uint32_t shiftT  = cntB - topBase;     // mod-2^32; top slot = excl + shiftT
    uint32_t tot = cntB + (uint32_t)NCOL - topBase;
    if (tot > SCAP) tot = SCAP;

    // ---- Scatter candidates directly to global-rank slots (cached bins) ----
    #pragma unroll
    for (int j = 0; j < VPT; j++) {
        int b = (int)((binPk[j >> 1] >> ((j & 1) * 16)) & 0xffffu);
        if (b <= B_lo || b >= B_hi) {
            uint32_t pos = atomicAdd(&sm.hist[HIX(b)], 1u);
            if (b >= B_hi) pos += shiftT;
            if (pos < SCAP) sm.sorted[pos] = v[j];
        }
    }
    __syncthreads();                                             // S5
    // now hist[b] = exclusive prefix + count = inclusive end (unshifted for top)

    // ---- Fix-up: rank within L1 bins, write to sorted2 (no WB hazard).
    //      8 independent chains/thread -> LDS latency well hidden ----
    #pragma unroll
    for (int it = 0; it < MAXS; it++) {
        int s = tid + it * NT;
        if (s < (int)tot) {
            float vv = sm.sorted[s];
            int b = bin1f(vv, mn, scale1);
            uint32_t en = sm.hist[HIX(b)];
            uint32_t st;
            if (s < (int)cntB) {
                st = (b == 0) ? 0u : sm.hist[HIX(b - 1)];
            } else {
                st = (b == B_hi) ? topBase : sm.hist[HIX(b - 1)];
                st += shiftT; en += shiftT;
            }
            if (en > tot) en = tot;
            uint32_t r = 0;
            if (en - st > 1) {
                for (uint32_t q = st; q < en; q++) {
                    float u = sm.sorted[q];
                    r += (u < vv) || (u == vv && (int)q < s);
                }
            }
            uint32_t d = st + r;
            if (d < SCAP) sm.sorted2[d] = vv;
        }
    }
    __syncthreads();                                             // S6

    // sorted2[0..cntB) = global ranks 0..cntB-1; sorted2[cntB..tot) = top tail.
    // window i: left = sorted2[i]; right = sorted2[tot - NW + i]

    // ---- single-wave argmin: wave 0 reduces 513 windows (9/lane) with
    //      shuffles only -- no cross-wave phase, no extra barrier ----
    if (wid == 0) {
        const int topstart = (int)tot - NW;
        float lbest = __int_as_float(0x7F800000);   // +inf
        int   lidx  = 0x7FFFFFFF;
        for (int i = lane; i < NW; i += 64) {
            float len = sm.sorted2[topstart + i] - sm.sorted2[i];
            if (len < lbest) { lbest = len; lidx = i; }
        }
        #pragma unroll
        for (int off = 32; off > 0; off >>= 1) {
            float v2 = __shfl_down(lbest, off, 64);
            int   i2 = __shfl_down(lidx,  off, 64);
            if (v2 < lbest || (v2 == lbest && i2 < lidx)) { lbest = v2; lidx = i2; }
        }
        if (lane == 0) {
            out[row]        = sm.sorted2[lidx];             // left  = s[idx]
            out[ROWS + row] = sm.sorted2[topstart + lidx];  // right = s[idx+target-1]
        }
    }
}

extern "C" void kernel_launch(void* const* d_in, const int* in_sizes, int n_in,
                              void* d_out, int out_size, void* d_ws, size_t ws_size,
                              hipStream_t stream) {
    const float* x = (const float*)d_in[0];
    float* out = (float*)d_out;
    recall_window_kernel<<<ROWS, NT, 0, stream>>>(x, out);
}